// Round 2
// baseline (2040.909 us; speedup 1.0000x reference)
//
#include <hip/hip_runtime.h>

// DGMC: B=4, NS=NT=512, D_IN=128, C1=64, R=C2=32, E=32768, STEPS=10
// Pairwise MLP decomposition: upd[s,t] = mb2 + sum_j relu(Ps[s,j]-Pt[t,j])*mw2[j]
// with Ps = (o_s@mw1)+mb1, Pt = o_t@mw1.
// This round: 10-step loop fused into ONE persistent kernel (512 blocks co-resident,
// hand-rolled device-scope grid barrier, 3 barriers/step), row-softmax stats fused
// into the update stage (row values already in registers).

constexpr int kB = 4;
constexpr int kNS = 512;
constexpr int kNT = 512;
constexpr int kDin = 128;
constexpr int kC1 = 64;
constexpr int kR = 32;
constexpr int kC2 = 32;
constexpr int kE = 32768;
constexpr int kSteps = 10;
constexpr int kN = kB * kNS;  // 2048 nodes per side
constexpr int NBLK = 512;     // persistent grid: 2 blocks/CU on 256 CUs

// ---------------- CSR build ----------------
__global__ void k_hist(const int* __restrict__ ei_s, const int* __restrict__ ei_t,
                       int* __restrict__ deg) {
  int g = blockIdx.y;
  const int* dst = (g ? ei_t : ei_s) + kE;
  int e = blockIdx.x * 256 + threadIdx.x;
  atomicAdd(&deg[g * kN + dst[e]], 1);
}

__global__ void k_scan(const int* __restrict__ deg, int* __restrict__ off,
                       int* __restrict__ cur) {
  int g = blockIdx.x;
  const int* d = deg + g * kN;
  int* o = off + g * (kN + 1);
  int* c = cur + g * kN;
  __shared__ int sums[256];
  int tid = threadIdx.x;
  int loc[8];
  int s = 0;
#pragma unroll
  for (int i = 0; i < 8; ++i) { loc[i] = d[tid * 8 + i]; s += loc[i]; }
  sums[tid] = s;
  __syncthreads();
  for (int st = 1; st < 256; st <<= 1) {
    int v = (tid >= st) ? sums[tid - st] : 0;
    __syncthreads();
    sums[tid] += v;
    __syncthreads();
  }
  int base = (tid > 0) ? sums[tid - 1] : 0;
#pragma unroll
  for (int i = 0; i < 8; ++i) {
    int idx = tid * 8 + i;
    o[idx] = base;
    c[idx] = base;
    base += loc[i];
  }
  if (tid == 255) o[kN] = base;
}

__global__ void k_scatter(const int* __restrict__ ei_s, const int* __restrict__ ei_t,
                          const float* __restrict__ ea_s, const float* __restrict__ ea_t,
                          int* __restrict__ cur, int* __restrict__ srcs,
                          float* __restrict__ eaw) {
  int g = blockIdx.y;
  const int* ei = g ? ei_t : ei_s;
  const float* ea = g ? ea_t : ea_s;
  int e = blockIdx.x * 256 + threadIdx.x;
  int d = ei[kE + e];
  int srcv = ei[e];
  int pos = atomicAdd(&cur[g * kN + d], 1);
  srcs[g * kE + pos] = srcv;
  eaw[g * kE + pos] = ea[e];
}

// ---------------- psi with W1: h = relu((x + agg) @ W1) ----------------
__global__ __launch_bounds__(128) void k_psi1(
    const float* __restrict__ x_s, const float* __restrict__ x_t,
    const int* __restrict__ srcs, const float* __restrict__ eaw,
    const int* __restrict__ off, const float* __restrict__ W1, float* __restrict__ h) {
  int g = blockIdx.y;
  const float* x = g ? x_t : x_s;
  const int* sr = srcs + g * kE;
  const float* ew = eaw + g * kE;
  const int* o = off + g * (kN + 1);
  float* ho = h + (size_t)g * kN * kC1;
  int n = blockIdx.x, f = threadIdx.x;
  __shared__ float y[kDin];
  int beg = o[n], end = o[n + 1];
  float m = 0.f;
  for (int idx = beg; idx < end; ++idx)
    m += x[(size_t)sr[idx] * kDin + f] * ew[idx];
  y[f] = x[(size_t)n * kDin + f] + m;
  __syncthreads();
  if (f < kC1) {
    float acc = 0.f;
#pragma unroll 16
    for (int k = 0; k < kDin; ++k) acc += y[k] * W1[k * kC1 + f];
    ho[(size_t)n * kC1 + f] = fmaxf(acc, 0.f);
  }
}

// ---------------- S_hat0 = h_s @ h_t^T (per batch) ----------------
__global__ __launch_bounds__(256) void k_shat0(const float* __restrict__ h,
                                               float* __restrict__ Shat) {
  int b = blockIdx.z, s0 = blockIdx.y * 64, t0 = blockIdx.x * 64;
  const float* hs = h + (size_t)(b * kNS + s0) * kC1;
  const float* ht = h + (size_t)kN * kC1 + (size_t)(b * kNT + t0) * kC1;
  __shared__ float As[64 * 68];
  __shared__ float Bs[64 * 68];
  int tid = threadIdx.x;
#pragma unroll
  for (int k2 = 0; k2 < 4; ++k2) {
    int idx = tid + k2 * 256;
    int row = idx >> 4, c4 = idx & 15;
    float4 va = *(const float4*)(hs + (size_t)row * kC1 + c4 * 4);
    *(float4*)&As[row * 68 + c4 * 4] = va;
    float4 vb = *(const float4*)(ht + (size_t)row * kC1 + c4 * 4);
    *(float4*)&Bs[row * 68 + c4 * 4] = vb;
  }
  __syncthreads();
  int ts = tid >> 4, tt = tid & 15;
  float acc[4][4] = {};
#pragma unroll
  for (int cc = 0; cc < 16; ++cc) {
    float4 a[4], bt[4];
#pragma unroll
    for (int i = 0; i < 4; ++i) a[i] = *(const float4*)&As[(ts * 4 + i) * 68 + cc * 4];
#pragma unroll
    for (int k = 0; k < 4; ++k) bt[k] = *(const float4*)&Bs[(tt + 16 * k) * 68 + cc * 4];
#pragma unroll
    for (int i = 0; i < 4; ++i)
#pragma unroll
      for (int k = 0; k < 4; ++k)
        acc[i][k] += a[i].x * bt[k].x + a[i].y * bt[k].y + a[i].z * bt[k].z + a[i].w * bt[k].w;
  }
#pragma unroll
  for (int i = 0; i < 4; ++i) {
    int s = s0 + ts * 4 + i;
    float* row = Shat + (size_t)(b * kNS + s) * kNT;
#pragma unroll
    for (int k = 0; k < 4; ++k) row[t0 + tt + 16 * k] = acc[i][k];
  }
}

// ---------------- row softmax -> dst ----------------
__global__ __launch_bounds__(256) void k_softmax(const float* __restrict__ Shat,
                                                 float* __restrict__ dst) {
  int row = blockIdx.x, tid = threadIdx.x;
  const float* p = Shat + (size_t)row * kNT;
  float v0 = p[tid], v1 = p[tid + 256];
  __shared__ float sm[4];
  float mx = fmaxf(v0, v1);
#pragma unroll
  for (int o = 32; o; o >>= 1) mx = fmaxf(mx, __shfl_down(mx, o, 64));
  if ((tid & 63) == 0) sm[tid >> 6] = mx;
  __syncthreads();
  mx = fmaxf(fmaxf(sm[0], sm[1]), fmaxf(sm[2], sm[3]));
  float e0 = __expf(v0 - mx), e1 = __expf(v1 - mx);
  float s = e0 + e1;
  __syncthreads();
#pragma unroll
  for (int o = 32; o; o >>= 1) s += __shfl_down(s, o, 64);
  if ((tid & 63) == 0) sm[tid >> 6] = s;
  __syncthreads();
  float rinv = 1.f / (sm[0] + sm[1] + sm[2] + sm[3]);
  float* d = dst + (size_t)row * kNT;
  d[tid] = e0 * rinv;
  d[tid + 256] = e1 * rinv;
}

// ---------------- row stats (max, 1/sumexp) + zero rt (pre-loop) ----------
__global__ __launch_bounds__(256) void k_rowstats(const float* __restrict__ Shat,
                                                  float* __restrict__ rowm,
                                                  float* __restrict__ rowl,
                                                  float* __restrict__ rt) {
  int row = blockIdx.x, tid = threadIdx.x;
  const float* p = Shat + (size_t)row * kNT;
  float v0 = p[tid], v1 = p[tid + 256];
  __shared__ float sm[4];
  float mx = fmaxf(v0, v1);
#pragma unroll
  for (int o = 32; o; o >>= 1) mx = fmaxf(mx, __shfl_down(mx, o, 64));
  if ((tid & 63) == 0) sm[tid >> 6] = mx;
  __syncthreads();
  mx = fmaxf(fmaxf(sm[0], sm[1]), fmaxf(sm[2], sm[3]));
  float s = __expf(v0 - mx) + __expf(v1 - mx);
  __syncthreads();
#pragma unroll
  for (int o = 32; o; o >>= 1) s += __shfl_down(s, o, 64);
  if ((tid & 63) == 0) sm[tid >> 6] = s;
  __syncthreads();
  if (tid == 0) {
    rowm[row] = mx;
    rowl[row] = 1.f / (sm[0] + sm[1] + sm[2] + sm[3]);
  }
  if (tid < kR) rt[(size_t)row * kR + tid] = 0.f;
}

// ---------------- device helpers for the persistent loop kernel ----------
__device__ __forceinline__ void grid_bar(int* bar, int& mygen) {
  __syncthreads();
  if (threadIdx.x == 0) {
    __threadfence();  // release: drain my stores, write back L2 (device scope)
    mygen++;
    int a = __hip_atomic_fetch_add(&bar[0], 1, __ATOMIC_RELAXED, __HIP_MEMORY_SCOPE_AGENT);
    if (a == NBLK - 1) {
      __hip_atomic_store(&bar[0], 0, __ATOMIC_RELAXED, __HIP_MEMORY_SCOPE_AGENT);
      __hip_atomic_store(&bar[1], mygen, __ATOMIC_RELEASE, __HIP_MEMORY_SCOPE_AGENT);
    } else {
      while (__hip_atomic_load(&bar[1], __ATOMIC_RELAXED, __HIP_MEMORY_SCOPE_AGENT) < mygen) {
        __builtin_amdgcn_s_sleep(1);
      }
    }
    __threadfence();  // acquire: invalidate L1/L2 so we see others' writes
  }
  __syncthreads();
}

// one wave computes P[n] = relu((vin[n] + agg) @ W2) @ mw1 (+mb1 if given)
__device__ __forceinline__ void psi2_node(
    int n, const float* __restrict__ vin, const int* __restrict__ sr,
    const float* __restrict__ ew, const int* __restrict__ o,
    const float* __restrict__ W2, const float* __restrict__ mw1,
    const float* __restrict__ mb1, float* __restrict__ Pout) {
  int lane = threadIdx.x & 63;
  int f = lane & 31, hh = lane >> 5;
  int beg = o[n], end = o[n + 1];
  float m = 0.f;
  for (int idx = beg + hh; idx < end; idx += 2)
    m += vin[(size_t)sr[idx] * kR + f] * ew[idx];
  m += __shfl_down(m, 32, 64);
  float v = vin[(size_t)n * kR + f] + m;  // valid on lanes 0..31
  float acc = 0.f;
#pragma unroll
  for (int k = 0; k < kC2; ++k) acc += __shfl(v, k, 64) * W2[k * kC2 + f];
  float ov = fmaxf(acc, 0.f);
  float p = mb1 ? mb1[f] : 0.f;
#pragma unroll
  for (int k = 0; k < kC2; ++k) p += __shfl(ov, k, 64) * mw1[k * kC2 + f];
  if (lane < 32) Pout[(size_t)n * kC2 + f] = p;
}

// ---------------- persistent 10-step loop kernel ----------------
__global__ __launch_bounds__(256, 2) void k_loop(
    float* __restrict__ Shat, const float* __restrict__ r,
    const int* __restrict__ srcs, const float* __restrict__ eaw,
    const int* __restrict__ off, const float* __restrict__ W2,
    const float* __restrict__ mw1, const float* __restrict__ mb1,
    const float* __restrict__ mw2, const float* __restrict__ mb2,
    float* __restrict__ rowm, float* __restrict__ rowl, float* __restrict__ rt,
    float* __restrict__ Ps, float* __restrict__ Pt, int* __restrict__ bar) {
  __shared__ float smem[3104];  // S1: Wt[32*64] + rch[32*32]; S3: red[32]
  int tid = threadIdx.x, b = blockIdx.x;
  int mygen = 0;

  for (int i = 0; i < kSteps; ++i) {
    const float* ri = r + (size_t)i * kN * kR;

    // ---- S1: partial r_t = S^T r over 32s x 64t tiles (atomic finish) ----
    {
      int tx = b & 7, ty = (b >> 3) & 15, bz = b >> 7;
      int t0 = tx * 64;
      int sg = bz * kNS + ty * 32;
#pragma unroll
      for (int k2 = 0; k2 < 2; ++k2) {
        int idx = tid + k2 * 256;        // 512 float4 = 32 rows x 64 cols
        int row = idx >> 4, c4 = idx & 15;
        int grow = sg + row;
        float4 v = *(const float4*)(Shat + (size_t)grow * kNT + t0 + c4 * 4);
        float m = rowm[grow], l = rowl[grow];
        float4 wv;
        wv.x = __expf(v.x - m) * l;
        wv.y = __expf(v.y - m) * l;
        wv.z = __expf(v.z - m) * l;
        wv.w = __expf(v.w - m) * l;
        *(float4*)&smem[row * 64 + c4 * 4] = wv;
      }
      {
        int row = tid >> 3, c4 = tid & 7;  // 256 float4 = 32 rows x 32
        float4 v = *(const float4*)(ri + (size_t)(sg + row) * kR + c4 * 4);
        *(float4*)&smem[2048 + row * 32 + c4 * 4] = v;
      }
      __syncthreads();
      int t_l = tid & 63, jg = tid >> 6;  // lane=t, wave=8-wide r group
      float acc[8] = {};
      for (int s = 0; s < 32; ++s) {
        float wv = smem[s * 64 + t_l];
        const float* rr = &smem[2048 + s * 32 + jg * 8];
        float4 ra = *(const float4*)rr;
        float4 rb = *(const float4*)(rr + 4);
        acc[0] += wv * ra.x; acc[1] += wv * ra.y; acc[2] += wv * ra.z; acc[3] += wv * ra.w;
        acc[4] += wv * rb.x; acc[5] += wv * rb.y; acc[6] += wv * rb.z; acc[7] += wv * rb.w;
      }
      float* dst = rt + (size_t)(bz * kNT + t0 + t_l) * kR + jg * 8;
#pragma unroll
      for (int q = 0; q < 8; ++q) atomicAdd(&dst[q], acc[q]);
    }
    grid_bar(bar, mygen);

    // ---- S2: Ps (from r_i, s-graph) and Pt (from r_t, t-graph), 1 node/wave --
    {
      int n = b * 4 + (tid >> 6);
      psi2_node(n, ri, srcs, eaw, off, W2, mw1, mb1, Ps);
      psi2_node(n, rt, srcs + kE, eaw + kE, off + (kN + 1), W2, mw1, nullptr, Pt);
    }
    grid_bar(bar, mygen);

    // ---- S3: Shat += upd, fused row stats (max, 1/sumexp), zero rt ----
    {
      int g0 = b * 4, bb = g0 >> 9;
      const float* PtB = Pt + (size_t)bb * kNT * kC2;
      int c0 = tid, c1 = tid + 256;
      float pt0[32], pt1[32];
#pragma unroll
      for (int q = 0; q < 8; ++q) {
        float4 a = *(const float4*)(PtB + (size_t)c0 * kC2 + q * 4);
        pt0[q * 4 + 0] = a.x; pt0[q * 4 + 1] = a.y; pt0[q * 4 + 2] = a.z; pt0[q * 4 + 3] = a.w;
        float4 c = *(const float4*)(PtB + (size_t)c1 * kC2 + q * 4);
        pt1[q * 4 + 0] = c.x; pt1[q * 4 + 1] = c.y; pt1[q * 4 + 2] = c.z; pt1[q * 4 + 3] = c.w;
      }
      float w2r[32];
#pragma unroll
      for (int j = 0; j < 32; ++j) w2r[j] = mw2[j];  // uniform -> scalar loads
      float bias = mb2[0];
      float nv0[4], nv1[4];
#pragma unroll
      for (int s = 0; s < 4; ++s) {
        const float* psr = Ps + (size_t)(g0 + s) * kC2;  // uniform row
        float u0 = 0.f, u1 = 0.f;
#pragma unroll
        for (int j = 0; j < 32; ++j) {
          float pv = psr[j];
          u0 += fmaxf(pv - pt0[j], 0.f) * w2r[j];
          u1 += fmaxf(pv - pt1[j], 0.f) * w2r[j];
        }
        float* srow = Shat + (size_t)(g0 + s) * kNT;
        float a = srow[c0] + u0 + bias;
        float bv = srow[c1] + u1 + bias;
        srow[c0] = a;
        srow[c1] = bv;
        nv0[s] = a;
        nv1[s] = bv;
      }
      // fused row stats for next step's S1
      float* red = smem;
      int wv_ = tid >> 6, ln = tid & 63;
#pragma unroll
      for (int s = 0; s < 4; ++s) {
        float m = fmaxf(nv0[s], nv1[s]);
#pragma unroll
        for (int o2 = 32; o2; o2 >>= 1) m = fmaxf(m, __shfl_down(m, o2, 64));
        if (ln == 0) red[s * 4 + wv_] = m;
      }
      __syncthreads();
      float mx[4];
#pragma unroll
      for (int s = 0; s < 4; ++s)
        mx[s] = fmaxf(fmaxf(red[s * 4], red[s * 4 + 1]), fmaxf(red[s * 4 + 2], red[s * 4 + 3]));
#pragma unroll
      for (int s = 0; s < 4; ++s) {
        float e = __expf(nv0[s] - mx[s]) + __expf(nv1[s] - mx[s]);
#pragma unroll
        for (int o2 = 32; o2; o2 >>= 1) e += __shfl_down(e, o2, 64);
        if (ln == 0) red[16 + s * 4 + wv_] = e;
      }
      __syncthreads();
      if (tid < 4) {
        int s = tid;
        float l = red[16 + s * 4] + red[16 + s * 4 + 1] + red[16 + s * 4 + 2] + red[16 + s * 4 + 3];
        rowm[g0 + s] = mx[s];
        rowl[g0 + s] = 1.f / l;
      }
      if (tid < 128) rt[(size_t)b * 128 + tid] = 0.f;  // zero rt for next S1
    }
    grid_bar(bar, mygen);
  }
}

extern "C" void kernel_launch(void* const* d_in, const int* in_sizes, int n_in,
                              void* d_out, int out_size, void* d_ws, size_t ws_size,
                              hipStream_t stream) {
  (void)in_sizes; (void)n_in; (void)out_size; (void)ws_size;
  const float* x_s = (const float*)d_in[0];
  const int* ei_s = (const int*)d_in[1];
  const float* ea_s = (const float*)d_in[2];
  const float* x_t = (const float*)d_in[4];
  const int* ei_t = (const int*)d_in[5];
  const float* ea_t = (const float*)d_in[6];
  const float* W1 = (const float*)d_in[8];
  const float* W2 = (const float*)d_in[9];
  const float* mw1 = (const float*)d_in[10];
  const float* mb1 = (const float*)d_in[11];
  const float* mw2 = (const float*)d_in[12];
  const float* mb2 = (const float*)d_in[13];
  const float* r = (const float*)d_in[14];
  float* out = (float*)d_out;

  char* w = (char*)d_ws;
  auto alloc = [&](size_t bytes) -> void* {
    void* p = (void*)w;
    w += (bytes + 255) & ~(size_t)255;
    return p;
  };
  int* deg = (int*)alloc((size_t)2 * kN * 4);
  int* off = (int*)alloc((size_t)2 * (kN + 1) * 4);
  int* cur = (int*)alloc((size_t)2 * kN * 4);
  int* srcs = (int*)alloc((size_t)2 * kE * 4);
  float* eaw = (float*)alloc((size_t)2 * kE * 4);
  float* h = (float*)alloc((size_t)2 * kN * kC1 * 4);
  float* Shat = (float*)alloc((size_t)kB * kNS * kNT * 4);
  float* rowm = (float*)alloc((size_t)kN * 4);
  float* rowl = (float*)alloc((size_t)kN * 4);
  float* rt = (float*)alloc((size_t)kN * kR * 4);
  float* Ps = (float*)alloc((size_t)kN * kC2 * 4);
  float* Pt = (float*)alloc((size_t)kN * kC2 * 4);
  int* bar = (int*)alloc(256);

  hipMemsetAsync(deg, 0, (size_t)2 * kN * 4, stream);
  hipMemsetAsync(bar, 0, 256, stream);
  k_hist<<<dim3(kE / 256, 2), 256, 0, stream>>>(ei_s, ei_t, deg);
  k_scan<<<2, 256, 0, stream>>>(deg, off, cur);
  k_scatter<<<dim3(kE / 256, 2), 256, 0, stream>>>(ei_s, ei_t, ea_s, ea_t, cur, srcs, eaw);
  k_psi1<<<dim3(kN, 2), 128, 0, stream>>>(x_s, x_t, srcs, eaw, off, W1, h);
  k_shat0<<<dim3(8, 8, kB), 256, 0, stream>>>(h, Shat);
  k_softmax<<<kN, 256, 0, stream>>>(Shat, out);  // S_0
  k_rowstats<<<kN, 256, 0, stream>>>(Shat, rowm, rowl, rt);
  k_loop<<<NBLK, 256, 0, stream>>>(Shat, r, srcs, eaw, off, W2, mw1, mb1, mw2, mb2,
                                   rowm, rowl, rt, Ps, Pt, bar);
  k_softmax<<<kN, 256, 0, stream>>>(Shat, out + (size_t)kB * kNS * kNT);  // S_L
}

// Round 3
// 1680.774 us; speedup vs baseline: 1.2143x; 1.2143x over previous
//
#include <hip/hip_runtime.h>

// DGMC: B=4, NS=NT=512, D_IN=128, C1=64, R=C2=32, E=32768, STEPS=10
// Pairwise MLP decomposition: upd[s,t] = mb2 + sum_j relu(Ps[s,j]-Pt[t,j])*mw2[j]
//   with Ps = (o_s@mw1)+mb1, Pt = o_t@mw1.
// Round 3: 2 dispatches/step. k_upd fuses {Shat update, row softmax stats,
// partial rt_{i+1} = S^T r_{i+1} accumulation} -- Shat read once per step.
// (Round-2 lesson: software grid barriers cost ~60us each on 8-XCD MI355X
//  due to per-block L2 writeback/invalidate; kernel boundaries are cheaper.)

constexpr int kB = 4;
constexpr int kNS = 512;
constexpr int kNT = 512;
constexpr int kDin = 128;
constexpr int kC1 = 64;
constexpr int kR = 32;
constexpr int kC2 = 32;
constexpr int kE = 32768;
constexpr int kSteps = 10;
constexpr int kN = kB * kNS;  // 2048 nodes per side

// ---------------- CSR build ----------------
__global__ void k_hist(const int* __restrict__ ei_s, const int* __restrict__ ei_t,
                       int* __restrict__ deg) {
  int g = blockIdx.y;
  const int* dst = (g ? ei_t : ei_s) + kE;
  int e = blockIdx.x * 256 + threadIdx.x;
  atomicAdd(&deg[g * kN + dst[e]], 1);
}

__global__ void k_scan(const int* __restrict__ deg, int* __restrict__ off,
                       int* __restrict__ cur) {
  int g = blockIdx.x;
  const int* d = deg + g * kN;
  int* o = off + g * (kN + 1);
  int* c = cur + g * kN;
  __shared__ int sums[256];
  int tid = threadIdx.x;
  int loc[8];
  int s = 0;
#pragma unroll
  for (int i = 0; i < 8; ++i) { loc[i] = d[tid * 8 + i]; s += loc[i]; }
  sums[tid] = s;
  __syncthreads();
  for (int st = 1; st < 256; st <<= 1) {
    int v = (tid >= st) ? sums[tid - st] : 0;
    __syncthreads();
    sums[tid] += v;
    __syncthreads();
  }
  int base = (tid > 0) ? sums[tid - 1] : 0;
#pragma unroll
  for (int i = 0; i < 8; ++i) {
    int idx = tid * 8 + i;
    o[idx] = base;
    c[idx] = base;
    base += loc[i];
  }
  if (tid == 255) o[kN] = base;
}

__global__ void k_scatter(const int* __restrict__ ei_s, const int* __restrict__ ei_t,
                          const float* __restrict__ ea_s, const float* __restrict__ ea_t,
                          int* __restrict__ cur, int* __restrict__ srcs,
                          float* __restrict__ eaw) {
  int g = blockIdx.y;
  const int* ei = g ? ei_t : ei_s;
  const float* ea = g ? ea_t : ea_s;
  int e = blockIdx.x * 256 + threadIdx.x;
  int d = ei[kE + e];
  int srcv = ei[e];
  int pos = atomicAdd(&cur[g * kN + d], 1);
  srcs[g * kE + pos] = srcv;
  eaw[g * kE + pos] = ea[e];
}

// ---------------- psi with W1: h = relu((x + agg) @ W1) ----------------
__global__ __launch_bounds__(128) void k_psi1(
    const float* __restrict__ x_s, const float* __restrict__ x_t,
    const int* __restrict__ srcs, const float* __restrict__ eaw,
    const int* __restrict__ off, const float* __restrict__ W1, float* __restrict__ h) {
  int g = blockIdx.y;
  const float* x = g ? x_t : x_s;
  const int* sr = srcs + g * kE;
  const float* ew = eaw + g * kE;
  const int* o = off + g * (kN + 1);
  float* ho = h + (size_t)g * kN * kC1;
  int n = blockIdx.x, f = threadIdx.x;
  __shared__ float y[kDin];
  int beg = o[n], end = o[n + 1];
  float m = 0.f;
  for (int idx = beg; idx < end; ++idx)
    m += x[(size_t)sr[idx] * kDin + f] * ew[idx];
  y[f] = x[(size_t)n * kDin + f] + m;
  __syncthreads();
  if (f < kC1) {
    float acc = 0.f;
#pragma unroll 16
    for (int k = 0; k < kDin; ++k) acc += y[k] * W1[k * kC1 + f];
    ho[(size_t)n * kC1 + f] = fmaxf(acc, 0.f);
  }
}

// ---------------- S_hat0 = h_s @ h_t^T (per batch) ----------------
__global__ __launch_bounds__(256) void k_shat0(const float* __restrict__ h,
                                               float* __restrict__ Shat) {
  int b = blockIdx.z, s0 = blockIdx.y * 64, t0 = blockIdx.x * 64;
  const float* hs = h + (size_t)(b * kNS + s0) * kC1;
  const float* ht = h + (size_t)kN * kC1 + (size_t)(b * kNT + t0) * kC1;
  __shared__ float As[64 * 68];
  __shared__ float Bs[64 * 68];
  int tid = threadIdx.x;
#pragma unroll
  for (int k2 = 0; k2 < 4; ++k2) {
    int idx = tid + k2 * 256;
    int row = idx >> 4, c4 = idx & 15;
    float4 va = *(const float4*)(hs + (size_t)row * kC1 + c4 * 4);
    *(float4*)&As[row * 68 + c4 * 4] = va;
    float4 vb = *(const float4*)(ht + (size_t)row * kC1 + c4 * 4);
    *(float4*)&Bs[row * 68 + c4 * 4] = vb;
  }
  __syncthreads();
  int ts = tid >> 4, tt = tid & 15;
  float acc[4][4] = {};
#pragma unroll
  for (int cc = 0; cc < 16; ++cc) {
    float4 a[4], bt[4];
#pragma unroll
    for (int i = 0; i < 4; ++i) a[i] = *(const float4*)&As[(ts * 4 + i) * 68 + cc * 4];
#pragma unroll
    for (int k = 0; k < 4; ++k) bt[k] = *(const float4*)&Bs[(tt + 16 * k) * 68 + cc * 4];
#pragma unroll
    for (int i = 0; i < 4; ++i)
#pragma unroll
      for (int k = 0; k < 4; ++k)
        acc[i][k] += a[i].x * bt[k].x + a[i].y * bt[k].y + a[i].z * bt[k].z + a[i].w * bt[k].w;
  }
#pragma unroll
  for (int i = 0; i < 4; ++i) {
    int s = s0 + ts * 4 + i;
    float* row = Shat + (size_t)(b * kNS + s) * kNT;
#pragma unroll
    for (int k = 0; k < 4; ++k) row[t0 + tt + 16 * k] = acc[i][k];
  }
}

// ---------------- row softmax -> dst (optionally also writes row stats) ----
__global__ __launch_bounds__(256) void k_softmax(const float* __restrict__ Shat,
                                                 float* __restrict__ dst,
                                                 float* __restrict__ rowm,
                                                 float* __restrict__ rowl) {
  int row = blockIdx.x, tid = threadIdx.x;
  const float* p = Shat + (size_t)row * kNT;
  float v0 = p[tid], v1 = p[tid + 256];
  __shared__ float sm[4];
  float mx = fmaxf(v0, v1);
#pragma unroll
  for (int o = 32; o; o >>= 1) mx = fmaxf(mx, __shfl_down(mx, o, 64));
  if ((tid & 63) == 0) sm[tid >> 6] = mx;
  __syncthreads();
  mx = fmaxf(fmaxf(sm[0], sm[1]), fmaxf(sm[2], sm[3]));
  float e0 = __expf(v0 - mx), e1 = __expf(v1 - mx);
  float s = e0 + e1;
  __syncthreads();
#pragma unroll
  for (int o = 32; o; o >>= 1) s += __shfl_down(s, o, 64);
  if ((tid & 63) == 0) sm[tid >> 6] = s;
  __syncthreads();
  float rinv = 1.f / (sm[0] + sm[1] + sm[2] + sm[3]);
  if (tid == 0) { rowm[row] = mx; rowl[row] = rinv; }
  float* d = dst + (size_t)row * kNT;
  d[tid] = e0 * rinv;
  d[tid + 256] = e1 * rinv;
}

// ---------------- rt0 = S_0^T @ r_0 (tiled partial, atomic finish) --------
__global__ __launch_bounds__(256) void k_rt(const float* __restrict__ Shat,
                                            const float* __restrict__ rowm,
                                            const float* __restrict__ rowl,
                                            const float* __restrict__ ri,
                                            float* __restrict__ rt) {
  int b = blockIdx.z, s0 = blockIdx.y * 64, t0 = blockIdx.x * 64;
  __shared__ float Wt[64 * 64];
  __shared__ float rch[64 * 32];
  int tid = threadIdx.x;
#pragma unroll
  for (int k2 = 0; k2 < 4; ++k2) {
    int idx = tid + k2 * 256;
    int row = idx >> 4, c4 = idx & 15;
    int grow = b * kNS + s0 + row;
    float4 v = *(const float4*)(Shat + (size_t)grow * kNT + t0 + c4 * 4);
    float m = rowm[grow], l = rowl[grow];
    float4 wv;
    wv.x = __expf(v.x - m) * l;
    wv.y = __expf(v.y - m) * l;
    wv.z = __expf(v.z - m) * l;
    wv.w = __expf(v.w - m) * l;
    *(float4*)&Wt[row * 64 + c4 * 4] = wv;
  }
#pragma unroll
  for (int k2 = 0; k2 < 2; ++k2) {
    int idx = tid + k2 * 256;
    int row = idx >> 3, c4 = idx & 7;
    float4 v = *(const float4*)(ri + (size_t)(b * kNS + s0 + row) * kR + c4 * 4);
    *(float4*)&rch[row * 32 + c4 * 4] = v;
  }
  __syncthreads();
  int t_l = tid & 63, jg = tid >> 6;
  float acc[8] = {};
  for (int s = 0; s < 64; ++s) {
    float wv = Wt[s * 64 + t_l];
    float4 ra = *(const float4*)&rch[s * 32 + jg * 8];
    float4 rb = *(const float4*)&rch[s * 32 + jg * 8 + 4];
    acc[0] += wv * ra.x; acc[1] += wv * ra.y; acc[2] += wv * ra.z; acc[3] += wv * ra.w;
    acc[4] += wv * rb.x; acc[5] += wv * rb.y; acc[6] += wv * rb.z; acc[7] += wv * rb.w;
  }
  float* dst = rt + (size_t)(b * kNT + t0 + t_l) * kR + jg * 8;
#pragma unroll
  for (int q = 0; q < 8; ++q) atomicAdd(&dst[q], acc[q]);
}

// ---------------- psi2: Ps = psi_s(r_i)@mw1+mb1 ; Pt = psi_t(rt)@mw1 -------
__device__ __forceinline__ void psi2_node(
    int n, const float* __restrict__ vin, const int* __restrict__ sr,
    const float* __restrict__ ew, const int* __restrict__ o,
    const float* __restrict__ W2, const float* __restrict__ mw1,
    const float* __restrict__ mb1, float* __restrict__ Pout) {
  int lane = threadIdx.x & 63;
  int f = lane & 31, hh = lane >> 5;
  int beg = o[n], end = o[n + 1];
  float m = 0.f;
  for (int idx = beg + hh; idx < end; idx += 2)
    m += vin[(size_t)sr[idx] * kR + f] * ew[idx];
  m += __shfl_down(m, 32, 64);
  float v = vin[(size_t)n * kR + f] + m;  // valid on lanes 0..31
  float acc = 0.f;
#pragma unroll
  for (int k = 0; k < kC2; ++k) acc += __shfl(v, k, 64) * W2[k * kC2 + f];
  float ov = fmaxf(acc, 0.f);
  float p = mb1 ? mb1[f] : 0.f;
#pragma unroll
  for (int k = 0; k < kC2; ++k) p += __shfl(ov, k, 64) * mw1[k * kC2 + f];
  if (lane < 32) Pout[(size_t)n * kC2 + f] = p;
}

__global__ __launch_bounds__(256) void k_psi2(
    const float* __restrict__ ri, const float* __restrict__ rtv,
    const int* __restrict__ srcs, const float* __restrict__ eaw,
    const int* __restrict__ off, const float* __restrict__ W2,
    const float* __restrict__ mw1, const float* __restrict__ mb1,
    float* __restrict__ Ps, float* __restrict__ Pt) {
  int n = blockIdx.x * 4 + (threadIdx.x >> 6);
  psi2_node(n, ri, srcs, eaw, off, W2, mw1, mb1, Ps);
  psi2_node(n, rtv, srcs + kE, eaw + kE, off + (kN + 1), W2, mw1, nullptr, Pt);
}

// ---- fused: Shat += upd ; row stats ; partial rt_next = S_next^T r_next ----
// grid 128 blocks x 512 threads; block handles 16 s-rows x all 512 t-cols.
__global__ __launch_bounds__(512, 4) void k_upd(
    float* __restrict__ Shat, const float* __restrict__ Ps,
    const float* __restrict__ Pt, const float* __restrict__ mw2,
    const float* __restrict__ mb2, const float* __restrict__ rnext,
    float* __restrict__ rt_acc, float* __restrict__ rt_zero, int doRt) {
  __shared__ float rn[16 * 32];
  __shared__ float red[16 * 8];
  __shared__ float lmx[16], linv[16];
  int tid = threadIdx.x, bid = blockIdx.x;
  int g0 = bid * 16;      // global s-row base (rows stay within one batch)
  int bb = g0 >> 9;       // batch index

  rt_zero[bid * 512 + tid] = 0.f;  // zero the rt buffer consumed by prior psi2
  if (doRt) rn[tid] = rnext[(size_t)g0 * kR + tid];  // 16 rows x 32 of r_next

  int c = tid;  // t column
  const float* PtB = Pt + ((size_t)bb * kNT + c) * kC2;
  float pt[32];
#pragma unroll
  for (int q = 0; q < 8; ++q) {
    float4 a = *(const float4*)(PtB + q * 4);
    pt[q * 4 + 0] = a.x; pt[q * 4 + 1] = a.y; pt[q * 4 + 2] = a.z; pt[q * 4 + 3] = a.w;
  }
  float bias = mb2[0];
  float nv[16];
#pragma unroll
  for (int s = 0; s < 16; ++s) {
    const float* psr = Ps + (size_t)(g0 + s) * kC2;  // uniform -> scalar loads
    float u = 0.f;
#pragma unroll
    for (int j = 0; j < 32; ++j)
      u += fmaxf(psr[j] - pt[j], 0.f) * mw2[j];
    float* srow = Shat + (size_t)(g0 + s) * kNT;
    float v = srow[c] + u + bias;
    srow[c] = v;
    nv[s] = v;
  }
  // row stats: max then sum(exp) across the 512 threads (8 waves)
  int wv = tid >> 6, ln = tid & 63;
#pragma unroll
  for (int s = 0; s < 16; ++s) {
    float m = nv[s];
#pragma unroll
    for (int o2 = 32; o2; o2 >>= 1) m = fmaxf(m, __shfl_down(m, o2, 64));
    if (ln == 0) red[s * 8 + wv] = m;
  }
  __syncthreads();
  if (tid < 16) {
    float m = red[tid * 8];
#pragma unroll
    for (int q = 1; q < 8; ++q) m = fmaxf(m, red[tid * 8 + q]);
    lmx[tid] = m;
  }
  __syncthreads();
#pragma unroll
  for (int s = 0; s < 16; ++s) {
    float e = __expf(nv[s] - lmx[s]);
    nv[s] = e;  // keep exp value for the rt pass
    float se = e;
#pragma unroll
    for (int o2 = 32; o2; o2 >>= 1) se += __shfl_down(se, o2, 64);
    if (ln == 0) red[s * 8 + wv] = se;
  }
  __syncthreads();
  if (tid < 16) {
    float se = red[tid * 8];
#pragma unroll
    for (int q = 1; q < 8; ++q) se += red[tid * 8 + q];
    linv[tid] = 1.f / se;
  }
  __syncthreads();
  if (doRt) {
    float acc[32] = {};
#pragma unroll
    for (int s = 0; s < 16; ++s) {
      float w = nv[s] * linv[s];  // softmax weight S_next[g0+s, c]
#pragma unroll
      for (int q = 0; q < 8; ++q) {
        float4 rv = *(const float4*)&rn[s * 32 + q * 4];
        acc[q * 4 + 0] += w * rv.x;
        acc[q * 4 + 1] += w * rv.y;
        acc[q * 4 + 2] += w * rv.z;
        acc[q * 4 + 3] += w * rv.w;
      }
    }
    float* dst = rt_acc + ((size_t)bb * kNT + c) * kR;
#pragma unroll
    for (int q = 0; q < 32; ++q) atomicAdd(&dst[q], acc[q]);
  }
}

extern "C" void kernel_launch(void* const* d_in, const int* in_sizes, int n_in,
                              void* d_out, int out_size, void* d_ws, size_t ws_size,
                              hipStream_t stream) {
  (void)in_sizes; (void)n_in; (void)out_size; (void)ws_size;
  const float* x_s = (const float*)d_in[0];
  const int* ei_s = (const int*)d_in[1];
  const float* ea_s = (const float*)d_in[2];
  const float* x_t = (const float*)d_in[4];
  const int* ei_t = (const int*)d_in[5];
  const float* ea_t = (const float*)d_in[6];
  const float* W1 = (const float*)d_in[8];
  const float* W2 = (const float*)d_in[9];
  const float* mw1 = (const float*)d_in[10];
  const float* mb1 = (const float*)d_in[11];
  const float* mw2 = (const float*)d_in[12];
  const float* mb2 = (const float*)d_in[13];
  const float* r = (const float*)d_in[14];
  float* out = (float*)d_out;

  char* w = (char*)d_ws;
  auto alloc = [&](size_t bytes) -> void* {
    void* p = (void*)w;
    w += (bytes + 255) & ~(size_t)255;
    return p;
  };
  // deg + rt double-buffer allocated contiguously -> single memset clears all
  int* deg = (int*)alloc((size_t)2 * kN * 4);            // 16384 B
  float* rt0 = (float*)alloc((size_t)kN * kR * 4);       // 262144 B
  float* rt1 = (float*)alloc((size_t)kN * kR * 4);       // 262144 B
  int* off = (int*)alloc((size_t)2 * (kN + 1) * 4);
  int* cur = (int*)alloc((size_t)2 * kN * 4);
  int* srcs = (int*)alloc((size_t)2 * kE * 4);
  float* eaw = (float*)alloc((size_t)2 * kE * 4);
  float* h = (float*)alloc((size_t)2 * kN * kC1 * 4);
  float* Shat = (float*)alloc((size_t)kB * kNS * kNT * 4);
  float* rowm = (float*)alloc((size_t)kN * 4);
  float* rowl = (float*)alloc((size_t)kN * 4);
  float* Ps = (float*)alloc((size_t)kN * kC2 * 4);
  float* Pt = (float*)alloc((size_t)kN * kC2 * 4);
  float* rtb[2] = {rt0, rt1};

  hipMemsetAsync(deg, 0, (size_t)(2 * kN + 2 * kN * kR) * 4, stream);
  k_hist<<<dim3(kE / 256, 2), 256, 0, stream>>>(ei_s, ei_t, deg);
  k_scan<<<2, 256, 0, stream>>>(deg, off, cur);
  k_scatter<<<dim3(kE / 256, 2), 256, 0, stream>>>(ei_s, ei_t, ea_s, ea_t, cur, srcs, eaw);
  k_psi1<<<dim3(kN, 2), 128, 0, stream>>>(x_s, x_t, srcs, eaw, off, W1, h);
  k_shat0<<<dim3(8, 8, kB), 256, 0, stream>>>(h, Shat);
  k_softmax<<<kN, 256, 0, stream>>>(Shat, out, rowm, rowl);          // S_0 + stats
  k_rt<<<dim3(8, 8, kB), 256, 0, stream>>>(Shat, rowm, rowl, r, rt0);  // rt_0
  for (int i = 0; i < kSteps; ++i) {
    const float* ri = r + (size_t)i * kN * kR;
    int doRt = (i + 1 < kSteps) ? 1 : 0;
    const float* rnext = doRt ? (ri + (size_t)kN * kR) : ri;  // valid ptr either way
    k_psi2<<<kN / 4, 256, 0, stream>>>(ri, rtb[i & 1], srcs, eaw, off, W2, mw1, mb1,
                                       Ps, Pt);
    k_upd<<<kN / 16, 512, 0, stream>>>(Shat, Ps, Pt, mw2, mb2, rnext,
                                       rtb[(i + 1) & 1], rtb[i & 1], doRt);
  }
  k_softmax<<<kN, 256, 0, stream>>>(Shat, out + (size_t)kB * kNS * kNT, rowm, rowl);
}

// Round 4
// 686.281 us; speedup vs baseline: 2.9739x; 2.4491x over previous
//
#include <hip/hip_runtime.h>

// DGMC: B=4, NS=NT=512, D_IN=128, C1=64, R=C2=32, E=32768, STEPS=10
// Pairwise MLP decomposition: upd[s,t] = mb2 + sum_j relu(Ps[s,j]-Pt[t,j])*mw2[j]
//   with Ps = (o_s@mw1)+mb1, Pt = o_t@mw1.
// Round 4: k_upd keeps the {update, row stats, rt-partial} fusion but the
// cross-block rt reduction is ATOMIC-FREE: per-chunk partial writes + k_red.
// (Round-3 lesson: 2M device-scope f32 atomics -> ~64MB memory-side RMW
//  traffic, 170us/kernel. Round-3 lesson #2: graph-replay dispatch overhead
//  is ~1-2us, so +10 small dispatches is cheap.)

constexpr int kB = 4;
constexpr int kNS = 512;
constexpr int kNT = 512;
constexpr int kDin = 128;
constexpr int kC1 = 64;
constexpr int kR = 32;
constexpr int kC2 = 32;
constexpr int kE = 32768;
constexpr int kSteps = 10;
constexpr int kN = kB * kNS;            // 2048 nodes per side
constexpr int kChunkStride = kN * kR;   // floats per partial chunk (64K)

// ---------------- CSR build ----------------
__global__ void k_hist(const int* __restrict__ ei_s, const int* __restrict__ ei_t,
                       int* __restrict__ deg) {
  int g = blockIdx.y;
  const int* dst = (g ? ei_t : ei_s) + kE;
  int e = blockIdx.x * 256 + threadIdx.x;
  atomicAdd(&deg[g * kN + dst[e]], 1);
}

__global__ void k_scan(const int* __restrict__ deg, int* __restrict__ off,
                       int* __restrict__ cur) {
  int g = blockIdx.x;
  const int* d = deg + g * kN;
  int* o = off + g * (kN + 1);
  int* c = cur + g * kN;
  __shared__ int sums[256];
  int tid = threadIdx.x;
  int loc[8];
  int s = 0;
#pragma unroll
  for (int i = 0; i < 8; ++i) { loc[i] = d[tid * 8 + i]; s += loc[i]; }
  sums[tid] = s;
  __syncthreads();
  for (int st = 1; st < 256; st <<= 1) {
    int v = (tid >= st) ? sums[tid - st] : 0;
    __syncthreads();
    sums[tid] += v;
    __syncthreads();
  }
  int base = (tid > 0) ? sums[tid - 1] : 0;
#pragma unroll
  for (int i = 0; i < 8; ++i) {
    int idx = tid * 8 + i;
    o[idx] = base;
    c[idx] = base;
    base += loc[i];
  }
  if (tid == 255) o[kN] = base;
}

__global__ void k_scatter(const int* __restrict__ ei_s, const int* __restrict__ ei_t,
                          const float* __restrict__ ea_s, const float* __restrict__ ea_t,
                          int* __restrict__ cur, int* __restrict__ srcs,
                          float* __restrict__ eaw) {
  int g = blockIdx.y;
  const int* ei = g ? ei_t : ei_s;
  const float* ea = g ? ea_t : ea_s;
  int e = blockIdx.x * 256 + threadIdx.x;
  int d = ei[kE + e];
  int srcv = ei[e];
  int pos = atomicAdd(&cur[g * kN + d], 1);
  srcs[g * kE + pos] = srcv;
  eaw[g * kE + pos] = ea[e];
}

// ---------------- psi with W1: h = relu((x + agg) @ W1) ----------------
__global__ __launch_bounds__(128) void k_psi1(
    const float* __restrict__ x_s, const float* __restrict__ x_t,
    const int* __restrict__ srcs, const float* __restrict__ eaw,
    const int* __restrict__ off, const float* __restrict__ W1, float* __restrict__ h) {
  int g = blockIdx.y;
  const float* x = g ? x_t : x_s;
  const int* sr = srcs + g * kE;
  const float* ew = eaw + g * kE;
  const int* o = off + g * (kN + 1);
  float* ho = h + (size_t)g * kN * kC1;
  int n = blockIdx.x, f = threadIdx.x;
  __shared__ float y[kDin];
  int beg = o[n], end = o[n + 1];
  float m = 0.f;
  for (int idx = beg; idx < end; ++idx)
    m += x[(size_t)sr[idx] * kDin + f] * ew[idx];
  y[f] = x[(size_t)n * kDin + f] + m;
  __syncthreads();
  if (f < kC1) {
    float acc = 0.f;
#pragma unroll 16
    for (int k = 0; k < kDin; ++k) acc += y[k] * W1[k * kC1 + f];
    ho[(size_t)n * kC1 + f] = fmaxf(acc, 0.f);
  }
}

// ---------------- S_hat0 = h_s @ h_t^T (per batch) ----------------
__global__ __launch_bounds__(256) void k_shat0(const float* __restrict__ h,
                                               float* __restrict__ Shat) {
  int b = blockIdx.z, s0 = blockIdx.y * 64, t0 = blockIdx.x * 64;
  const float* hs = h + (size_t)(b * kNS + s0) * kC1;
  const float* ht = h + (size_t)kN * kC1 + (size_t)(b * kNT + t0) * kC1;
  __shared__ float As[64 * 68];
  __shared__ float Bs[64 * 68];
  int tid = threadIdx.x;
#pragma unroll
  for (int k2 = 0; k2 < 4; ++k2) {
    int idx = tid + k2 * 256;
    int row = idx >> 4, c4 = idx & 15;
    float4 va = *(const float4*)(hs + (size_t)row * kC1 + c4 * 4);
    *(float4*)&As[row * 68 + c4 * 4] = va;
    float4 vb = *(const float4*)(ht + (size_t)row * kC1 + c4 * 4);
    *(float4*)&Bs[row * 68 + c4 * 4] = vb;
  }
  __syncthreads();
  int ts = tid >> 4, tt = tid & 15;
  float acc[4][4] = {};
#pragma unroll
  for (int cc = 0; cc < 16; ++cc) {
    float4 a[4], bt[4];
#pragma unroll
    for (int i = 0; i < 4; ++i) a[i] = *(const float4*)&As[(ts * 4 + i) * 68 + cc * 4];
#pragma unroll
    for (int k = 0; k < 4; ++k) bt[k] = *(const float4*)&Bs[(tt + 16 * k) * 68 + cc * 4];
#pragma unroll
    for (int i = 0; i < 4; ++i)
#pragma unroll
      for (int k = 0; k < 4; ++k)
        acc[i][k] += a[i].x * bt[k].x + a[i].y * bt[k].y + a[i].z * bt[k].z + a[i].w * bt[k].w;
  }
#pragma unroll
  for (int i = 0; i < 4; ++i) {
    int s = s0 + ts * 4 + i;
    float* row = Shat + (size_t)(b * kNS + s) * kNT;
#pragma unroll
    for (int k = 0; k < 4; ++k) row[t0 + tt + 16 * k] = acc[i][k];
  }
}

// ---------------- row softmax -> dst (also writes row stats) ----------
__global__ __launch_bounds__(256) void k_softmax(const float* __restrict__ Shat,
                                                 float* __restrict__ dst,
                                                 float* __restrict__ rowm,
                                                 float* __restrict__ rowl) {
  int row = blockIdx.x, tid = threadIdx.x;
  const float* p = Shat + (size_t)row * kNT;
  float v0 = p[tid], v1 = p[tid + 256];
  __shared__ float sm[4];
  float mx = fmaxf(v0, v1);
#pragma unroll
  for (int o = 32; o; o >>= 1) mx = fmaxf(mx, __shfl_down(mx, o, 64));
  if ((tid & 63) == 0) sm[tid >> 6] = mx;
  __syncthreads();
  mx = fmaxf(fmaxf(sm[0], sm[1]), fmaxf(sm[2], sm[3]));
  float e0 = __expf(v0 - mx), e1 = __expf(v1 - mx);
  float s = e0 + e1;
  __syncthreads();
#pragma unroll
  for (int o = 32; o; o >>= 1) s += __shfl_down(s, o, 64);
  if ((tid & 63) == 0) sm[tid >> 6] = s;
  __syncthreads();
  float rinv = 1.f / (sm[0] + sm[1] + sm[2] + sm[3]);
  if (tid == 0) { rowm[row] = mx; rowl[row] = rinv; }
  float* d = dst + (size_t)row * kNT;
  d[tid] = e0 * rinv;
  d[tid + 256] = e1 * rinv;
}

// -------- rt0 partials: part[by] += S_0^T r_0 over 64-s chunks (no atomics) --
__global__ __launch_bounds__(256) void k_rt0(const float* __restrict__ Shat,
                                             const float* __restrict__ rowm,
                                             const float* __restrict__ rowl,
                                             const float* __restrict__ ri,
                                             float* __restrict__ part) {
  int b = blockIdx.z, cs = blockIdx.y, s0 = cs * 64, t0 = blockIdx.x * 64;
  __shared__ float Wt[64 * 64];
  __shared__ float rch[64 * 32];
  int tid = threadIdx.x;
#pragma unroll
  for (int k2 = 0; k2 < 4; ++k2) {
    int idx = tid + k2 * 256;
    int row = idx >> 4, c4 = idx & 15;
    int grow = b * kNS + s0 + row;
    float4 v = *(const float4*)(Shat + (size_t)grow * kNT + t0 + c4 * 4);
    float m = rowm[grow], l = rowl[grow];
    float4 wv;
    wv.x = __expf(v.x - m) * l;
    wv.y = __expf(v.y - m) * l;
    wv.z = __expf(v.z - m) * l;
    wv.w = __expf(v.w - m) * l;
    *(float4*)&Wt[row * 64 + c4 * 4] = wv;
  }
#pragma unroll
  for (int k2 = 0; k2 < 2; ++k2) {
    int idx = tid + k2 * 256;
    int row = idx >> 3, c4 = idx & 7;
    float4 v = *(const float4*)(ri + (size_t)(b * kNS + s0 + row) * kR + c4 * 4);
    *(float4*)&rch[row * 32 + c4 * 4] = v;
  }
  __syncthreads();
  int t_l = tid & 63, jg = tid >> 6;
  float acc[8] = {};
  for (int s = 0; s < 64; ++s) {
    float wv = Wt[s * 64 + t_l];
    float4 ra = *(const float4*)&rch[s * 32 + jg * 8];
    float4 rb = *(const float4*)&rch[s * 32 + jg * 8 + 4];
    acc[0] += wv * ra.x; acc[1] += wv * ra.y; acc[2] += wv * ra.z; acc[3] += wv * ra.w;
    acc[4] += wv * rb.x; acc[5] += wv * rb.y; acc[6] += wv * rb.z; acc[7] += wv * rb.w;
  }
  float* dst = part + (size_t)cs * kChunkStride +
               (size_t)(b * kNT + t0 + t_l) * kR + jg * 8;
  *(float4*)dst = make_float4(acc[0], acc[1], acc[2], acc[3]);
  *(float4*)(dst + 4) = make_float4(acc[4], acc[5], acc[6], acc[7]);
}

// ---------------- reduce partial chunks -> rt ----------------
__global__ __launch_bounds__(256) void k_red(const float* __restrict__ part,
                                             float* __restrict__ rt, int nc) {
  int g = blockIdx.x * 256 + threadIdx.x;  // float4 index, 16384 total
  const float4* p4 = (const float4*)part;
  float4 s = make_float4(0.f, 0.f, 0.f, 0.f);
  for (int cs = 0; cs < nc; ++cs) {
    float4 v = p4[(size_t)cs * (kChunkStride / 4) + g];
    s.x += v.x; s.y += v.y; s.z += v.z; s.w += v.w;
  }
  ((float4*)rt)[g] = s;
}

// ---------------- psi2: Ps = psi_s(r_i)@mw1+mb1 ; Pt = psi_t(rt)@mw1 -------
__device__ __forceinline__ void psi2_node(
    int n, const float* __restrict__ vin, const int* __restrict__ sr,
    const float* __restrict__ ew, const int* __restrict__ o,
    const float* __restrict__ W2, const float* __restrict__ mw1,
    const float* __restrict__ mb1, float* __restrict__ Pout) {
  int lane = threadIdx.x & 63;
  int f = lane & 31, hh = lane >> 5;
  int beg = o[n], end = o[n + 1];
  float m = 0.f;
  for (int idx = beg + hh; idx < end; idx += 2)
    m += vin[(size_t)sr[idx] * kR + f] * ew[idx];
  m += __shfl_down(m, 32, 64);
  float v = vin[(size_t)n * kR + f] + m;  // valid on lanes 0..31
  float acc = 0.f;
#pragma unroll
  for (int k = 0; k < kC2; ++k) acc += __shfl(v, k, 64) * W2[k * kC2 + f];
  float ov = fmaxf(acc, 0.f);
  float p = mb1 ? mb1[f] : 0.f;
#pragma unroll
  for (int k = 0; k < kC2; ++k) p += __shfl(ov, k, 64) * mw1[k * kC2 + f];
  if (lane < 32) Pout[(size_t)n * kC2 + f] = p;
}

__global__ __launch_bounds__(256) void k_psi2(
    const float* __restrict__ ri, const float* __restrict__ rtv,
    const int* __restrict__ srcs, const float* __restrict__ eaw,
    const int* __restrict__ off, const float* __restrict__ W2,
    const float* __restrict__ mw1, const float* __restrict__ mb1,
    float* __restrict__ Ps, float* __restrict__ Pt) {
  int n = blockIdx.x * 4 + (threadIdx.x >> 6);
  psi2_node(n, ri, srcs, eaw, off, W2, mw1, mb1, Ps);
  psi2_node(n, rtv, srcs + kE, eaw + kE, off + (kN + 1), W2, mw1, nullptr, Pt);
}

// ---- fused: Shat += upd ; row stats ; rt partial (atomic-free) ----
// grid 128 blocks x 512 threads; block = 16 s-rows x all 512 t-cols.
__global__ __launch_bounds__(512, 4) void k_upd(
    float* __restrict__ Shat, const float* __restrict__ Ps,
    const float* __restrict__ Pt, const float* __restrict__ mw2,
    const float* __restrict__ mb2, const float* __restrict__ rnext,
    float* __restrict__ part, int doRt) {
  __shared__ float rn[16 * 32];
  __shared__ float red[16 * 8];
  __shared__ float lmx[16], linv[16];
  int tid = threadIdx.x, bid = blockIdx.x;
  int g0 = bid * 16;      // global s-row base (rows stay within one batch)
  int bb = g0 >> 9;       // batch index
  int cs = bid & 31;      // s-chunk index within batch

  if (doRt) rn[tid] = rnext[(size_t)g0 * kR + tid];  // 16 rows x 32 of r_next

  int c = tid;  // t column
  const float* PtB = Pt + ((size_t)bb * kNT + c) * kC2;
  float pt[32];
#pragma unroll
  for (int q = 0; q < 8; ++q) {
    float4 a = *(const float4*)(PtB + q * 4);
    pt[q * 4 + 0] = a.x; pt[q * 4 + 1] = a.y; pt[q * 4 + 2] = a.z; pt[q * 4 + 3] = a.w;
  }
  float bias = mb2[0];
  float nv[16];
#pragma unroll
  for (int s = 0; s < 16; ++s) {
    const float* psr = Ps + (size_t)(g0 + s) * kC2;  // uniform -> scalar loads
    float u = 0.f;
#pragma unroll
    for (int j = 0; j < 32; ++j)
      u += fmaxf(psr[j] - pt[j], 0.f) * mw2[j];
    float* srow = Shat + (size_t)(g0 + s) * kNT;
    float v = srow[c] + u + bias;
    srow[c] = v;
    nv[s] = v;
  }
  // row stats: max then sum(exp) across the 512 threads (8 waves)
  int wv = tid >> 6, ln = tid & 63;
#pragma unroll
  for (int s = 0; s < 16; ++s) {
    float m = nv[s];
#pragma unroll
    for (int o2 = 32; o2; o2 >>= 1) m = fmaxf(m, __shfl_down(m, o2, 64));
    if (ln == 0) red[s * 8 + wv] = m;
  }
  __syncthreads();
  if (tid < 16) {
    float m = red[tid * 8];
#pragma unroll
    for (int q = 1; q < 8; ++q) m = fmaxf(m, red[tid * 8 + q]);
    lmx[tid] = m;
  }
  __syncthreads();
#pragma unroll
  for (int s = 0; s < 16; ++s) {
    float e = __expf(nv[s] - lmx[s]);
    nv[s] = e;  // keep exp value for the rt pass
    float se = e;
#pragma unroll
    for (int o2 = 32; o2; o2 >>= 1) se += __shfl_down(se, o2, 64);
    if (ln == 0) red[s * 8 + wv] = se;
  }
  __syncthreads();
  if (tid < 16) {
    float se = red[tid * 8];
#pragma unroll
    for (int q = 1; q < 8; ++q) se += red[tid * 8 + q];
    linv[tid] = 1.f / se;
  }
  __syncthreads();
  if (doRt) {
    float acc[32] = {};
#pragma unroll
    for (int s = 0; s < 16; ++s) {
      float w = nv[s] * linv[s];  // softmax weight S_next[g0+s, c]
#pragma unroll
      for (int q = 0; q < 8; ++q) {
        float4 rv = *(const float4*)&rn[s * 32 + q * 4];
        acc[q * 4 + 0] += w * rv.x;
        acc[q * 4 + 1] += w * rv.y;
        acc[q * 4 + 2] += w * rv.z;
        acc[q * 4 + 3] += w * rv.w;
      }
    }
    float* dst = part + (size_t)cs * kChunkStride + ((size_t)bb * kNT + c) * kR;
#pragma unroll
    for (int q = 0; q < 8; ++q)
      *(float4*)(dst + q * 4) =
          make_float4(acc[q * 4], acc[q * 4 + 1], acc[q * 4 + 2], acc[q * 4 + 3]);
  }
}

extern "C" void kernel_launch(void* const* d_in, const int* in_sizes, int n_in,
                              void* d_out, int out_size, void* d_ws, size_t ws_size,
                              hipStream_t stream) {
  (void)in_sizes; (void)n_in; (void)out_size; (void)ws_size;
  const float* x_s = (const float*)d_in[0];
  const int* ei_s = (const int*)d_in[1];
  const float* ea_s = (const float*)d_in[2];
  const float* x_t = (const float*)d_in[4];
  const int* ei_t = (const int*)d_in[5];
  const float* ea_t = (const float*)d_in[6];
  const float* W1 = (const float*)d_in[8];
  const float* W2 = (const float*)d_in[9];
  const float* mw1 = (const float*)d_in[10];
  const float* mb1 = (const float*)d_in[11];
  const float* mw2 = (const float*)d_in[12];
  const float* mb2 = (const float*)d_in[13];
  const float* r = (const float*)d_in[14];
  float* out = (float*)d_out;

  char* w = (char*)d_ws;
  auto alloc = [&](size_t bytes) -> void* {
    void* p = (void*)w;
    w += (bytes + 255) & ~(size_t)255;
    return p;
  };
  int* deg = (int*)alloc((size_t)2 * kN * 4);
  int* off = (int*)alloc((size_t)2 * (kN + 1) * 4);
  int* cur = (int*)alloc((size_t)2 * kN * 4);
  int* srcs = (int*)alloc((size_t)2 * kE * 4);
  float* eaw = (float*)alloc((size_t)2 * kE * 4);
  float* h = (float*)alloc((size_t)2 * kN * kC1 * 4);
  float* Shat = (float*)alloc((size_t)kB * kNS * kNT * 4);
  float* rowm = (float*)alloc((size_t)kN * 4);
  float* rowl = (float*)alloc((size_t)kN * 4);
  float* rt = (float*)alloc((size_t)kN * kR * 4);
  float* Ps = (float*)alloc((size_t)kN * kC2 * 4);
  float* Pt = (float*)alloc((size_t)kN * kC2 * 4);
  float* part = (float*)alloc((size_t)32 * kChunkStride * 4);  // 8 MB

  hipMemsetAsync(deg, 0, (size_t)2 * kN * 4, stream);
  k_hist<<<dim3(kE / 256, 2), 256, 0, stream>>>(ei_s, ei_t, deg);
  k_scan<<<2, 256, 0, stream>>>(deg, off, cur);
  k_scatter<<<dim3(kE / 256, 2), 256, 0, stream>>>(ei_s, ei_t, ea_s, ea_t, cur, srcs, eaw);
  k_psi1<<<dim3(kN, 2), 128, 0, stream>>>(x_s, x_t, srcs, eaw, off, W1, h);
  k_shat0<<<dim3(8, 8, kB), 256, 0, stream>>>(h, Shat);
  k_softmax<<<kN, 256, 0, stream>>>(Shat, out, rowm, rowl);            // S_0 + stats
  k_rt0<<<dim3(8, 8, kB), 256, 0, stream>>>(Shat, rowm, rowl, r, part);  // 8 chunks
  k_red<<<kN * kR / 4 / 256, 256, 0, stream>>>(part, rt, 8);
  for (int i = 0; i < kSteps; ++i) {
    const float* ri = r + (size_t)i * kN * kR;
    int doRt = (i + 1 < kSteps) ? 1 : 0;
    const float* rnext = doRt ? (ri + (size_t)kN * kR) : ri;  // valid ptr either way
    k_psi2<<<kN / 4, 256, 0, stream>>>(ri, rt, srcs, eaw, off, W2, mw1, mb1, Ps, Pt);
    k_upd<<<kN / 16, 512, 0, stream>>>(Shat, Ps, Pt, mw2, mb2, rnext, part, doRt);
    if (doRt) k_red<<<kN * kR / 4 / 256, 256, 0, stream>>>(part, rt, 32);
  }
  k_softmax<<<kN, 256, 0, stream>>>(Shat, out + (size_t)kB * kNS * kNT, rowm, rowl);
}

// Round 5
// 485.727 us; speedup vs baseline: 4.2018x; 1.4129x over previous
//
#include <hip/hip_runtime.h>

// DGMC: B=4, NS=NT=512, D_IN=128, C1=64, R=C2=32, E=32768, STEPS=10
// Pairwise MLP decomposition: upd[s,t] = mb2 + sum_j relu(Ps[s,j]-Pt[t,j])*mw2[j]
//   with Ps = (o_s@mw1)+mb1, Pt = o_t@mw1.
// Round 5: k_upd de-fused from rt-partial and reshaped for occupancy
// (512 blocks, all CUs; round-4 version was 128 blocks = half the GPU idle,
// latency-bound at 9% occupancy). Pt staged via LDS (coalesced global reads,
// stride-33 banks ~conflict-free). rt partials computed by k_rt (tile kernel)
// in j-major layout -> fully coalesced stores; k_red sums 8 chunks.
// Per-step softmax stats: k_upd emits per-256-col-chunk partial (max,sumexp);
// k_rt combines the 2 chunks. Atomic-free everywhere (round-3 lesson).

constexpr int kB = 4;
constexpr int kNS = 512;
constexpr int kNT = 512;
constexpr int kDin = 128;
constexpr int kC1 = 64;
constexpr int kR = 32;
constexpr int kC2 = 32;
constexpr int kE = 32768;
constexpr int kSteps = 10;
constexpr int kN = kB * kNS;              // 2048 nodes per side
constexpr int kChunkStride = kR * kN;     // floats per rt partial chunk (65536)

// ---------------- CSR build ----------------
__global__ void k_hist(const int* __restrict__ ei_s, const int* __restrict__ ei_t,
                       int* __restrict__ deg) {
  int g = blockIdx.y;
  const int* dst = (g ? ei_t : ei_s) + kE;
  int e = blockIdx.x * 256 + threadIdx.x;
  atomicAdd(&deg[g * kN + dst[e]], 1);
}

__global__ void k_scan(const int* __restrict__ deg, int* __restrict__ off,
                       int* __restrict__ cur) {
  int g = blockIdx.x;
  const int* d = deg + g * kN;
  int* o = off + g * (kN + 1);
  int* c = cur + g * kN;
  __shared__ int sums[256];
  int tid = threadIdx.x;
  int loc[8];
  int s = 0;
#pragma unroll
  for (int i = 0; i < 8; ++i) { loc[i] = d[tid * 8 + i]; s += loc[i]; }
  sums[tid] = s;
  __syncthreads();
  for (int st = 1; st < 256; st <<= 1) {
    int v = (tid >= st) ? sums[tid - st] : 0;
    __syncthreads();
    sums[tid] += v;
    __syncthreads();
  }
  int base = (tid > 0) ? sums[tid - 1] : 0;
#pragma unroll
  for (int i = 0; i < 8; ++i) {
    int idx = tid * 8 + i;
    o[idx] = base;
    c[idx] = base;
    base += loc[i];
  }
  if (tid == 255) o[kN] = base;
}

__global__ void k_scatter(const int* __restrict__ ei_s, const int* __restrict__ ei_t,
                          const float* __restrict__ ea_s, const float* __restrict__ ea_t,
                          int* __restrict__ cur, int* __restrict__ srcs,
                          float* __restrict__ eaw) {
  int g = blockIdx.y;
  const int* ei = g ? ei_t : ei_s;
  const float* ea = g ? ea_t : ea_s;
  int e = blockIdx.x * 256 + threadIdx.x;
  int d = ei[kE + e];
  int srcv = ei[e];
  int pos = atomicAdd(&cur[g * kN + d], 1);
  srcs[g * kE + pos] = srcv;
  eaw[g * kE + pos] = ea[e];
}

// ---------------- psi with W1: h = relu((x + agg) @ W1) ----------------
__global__ __launch_bounds__(128) void k_psi1(
    const float* __restrict__ x_s, const float* __restrict__ x_t,
    const int* __restrict__ srcs, const float* __restrict__ eaw,
    const int* __restrict__ off, const float* __restrict__ W1, float* __restrict__ h) {
  int g = blockIdx.y;
  const float* x = g ? x_t : x_s;
  const int* sr = srcs + g * kE;
  const float* ew = eaw + g * kE;
  const int* o = off + g * (kN + 1);
  float* ho = h + (size_t)g * kN * kC1;
  int n = blockIdx.x, f = threadIdx.x;
  __shared__ float y[kDin];
  int beg = o[n], end = o[n + 1];
  float m = 0.f;
  for (int idx = beg; idx < end; ++idx)
    m += x[(size_t)sr[idx] * kDin + f] * ew[idx];
  y[f] = x[(size_t)n * kDin + f] + m;
  __syncthreads();
  if (f < kC1) {
    float acc = 0.f;
#pragma unroll 16
    for (int k = 0; k < kDin; ++k) acc += y[k] * W1[k * kC1 + f];
    ho[(size_t)n * kC1 + f] = fmaxf(acc, 0.f);
  }
}

// ---------------- S_hat0 = h_s @ h_t^T (per batch) ----------------
__global__ __launch_bounds__(256) void k_shat0(const float* __restrict__ h,
                                               float* __restrict__ Shat) {
  int b = blockIdx.z, s0 = blockIdx.y * 64, t0 = blockIdx.x * 64;
  const float* hs = h + (size_t)(b * kNS + s0) * kC1;
  const float* ht = h + (size_t)kN * kC1 + (size_t)(b * kNT + t0) * kC1;
  __shared__ float As[64 * 68];
  __shared__ float Bs[64 * 68];
  int tid = threadIdx.x;
#pragma unroll
  for (int k2 = 0; k2 < 4; ++k2) {
    int idx = tid + k2 * 256;
    int row = idx >> 4, c4 = idx & 15;
    float4 va = *(const float4*)(hs + (size_t)row * kC1 + c4 * 4);
    *(float4*)&As[row * 68 + c4 * 4] = va;
    float4 vb = *(const float4*)(ht + (size_t)row * kC1 + c4 * 4);
    *(float4*)&Bs[row * 68 + c4 * 4] = vb;
  }
  __syncthreads();
  int ts = tid >> 4, tt = tid & 15;
  float acc[4][4] = {};
#pragma unroll
  for (int cc = 0; cc < 16; ++cc) {
    float4 a[4], bt[4];
#pragma unroll
    for (int i = 0; i < 4; ++i) a[i] = *(const float4*)&As[(ts * 4 + i) * 68 + cc * 4];
#pragma unroll
    for (int k = 0; k < 4; ++k) bt[k] = *(const float4*)&Bs[(tt + 16 * k) * 68 + cc * 4];
#pragma unroll
    for (int i = 0; i < 4; ++i)
#pragma unroll
      for (int k = 0; k < 4; ++k)
        acc[i][k] += a[i].x * bt[k].x + a[i].y * bt[k].y + a[i].z * bt[k].z + a[i].w * bt[k].w;
  }
#pragma unroll
  for (int i = 0; i < 4; ++i) {
    int s = s0 + ts * 4 + i;
    float* row = Shat + (size_t)(b * kNS + s) * kNT;
#pragma unroll
    for (int k = 0; k < 4; ++k) row[t0 + tt + 16 * k] = acc[i][k];
  }
}

// ------- row softmax -> dst; also seeds pstat chunks (chunk1 = neutral) ----
__global__ __launch_bounds__(256) void k_softmax(const float* __restrict__ Shat,
                                                 float* __restrict__ dst,
                                                 float* __restrict__ pstatm,
                                                 float* __restrict__ pstatl) {
  int row = blockIdx.x, tid = threadIdx.x;
  const float* p = Shat + (size_t)row * kNT;
  float v0 = p[tid], v1 = p[tid + 256];
  __shared__ float sm[4];
  float mx = fmaxf(v0, v1);
#pragma unroll
  for (int o = 32; o; o >>= 1) mx = fmaxf(mx, __shfl_down(mx, o, 64));
  if ((tid & 63) == 0) sm[tid >> 6] = mx;
  __syncthreads();
  mx = fmaxf(fmaxf(sm[0], sm[1]), fmaxf(sm[2], sm[3]));
  float e0 = __expf(v0 - mx), e1 = __expf(v1 - mx);
  float s = e0 + e1;
  __syncthreads();
#pragma unroll
  for (int o = 32; o; o >>= 1) s += __shfl_down(s, o, 64);
  if ((tid & 63) == 0) sm[tid >> 6] = s;
  __syncthreads();
  float tot = sm[0] + sm[1] + sm[2] + sm[3];
  float rinv = 1.f / tot;
  if (tid == 0) {
    pstatm[row] = mx;
    pstatl[row] = tot;
    pstatm[kN + row] = -3.4e38f;  // neutral second chunk
    pstatl[kN + row] = 0.f;
  }
  float* d = dst + (size_t)row * kNT;
  d[tid] = e0 * rinv;
  d[tid + 256] = e1 * rinv;
}

// -------- rt partials: part[cs] = (64-s-chunk of S)^T r  (j-major, no atomics)
__global__ __launch_bounds__(256) void k_rt(const float* __restrict__ Shat,
                                            const float* __restrict__ pstatm,
                                            const float* __restrict__ pstatl,
                                            const float* __restrict__ ri,
                                            float* __restrict__ part) {
  int b = blockIdx.z, cs = blockIdx.y, s0 = cs * 64, t0 = blockIdx.x * 64;
  __shared__ float Wt[64 * 64];
  __shared__ float rch[64 * 32];
  __shared__ float lm[64], ll[64];
  int tid = threadIdx.x;
  if (tid < 64) {  // combine the 2 stat chunks for this block's 64 rows
    int row = b * kNS + s0 + tid;
    float m0 = pstatm[row], m1 = pstatm[kN + row];
    float l0 = pstatl[row], l1 = pstatl[kN + row];
    float m = fmaxf(m0, m1);
    lm[tid] = m;
    ll[tid] = 1.f / (__expf(m0 - m) * l0 + __expf(m1 - m) * l1);
  }
  __syncthreads();
#pragma unroll
  for (int k2 = 0; k2 < 4; ++k2) {
    int idx = tid + k2 * 256;
    int row = idx >> 4, c4 = idx & 15;
    int grow = b * kNS + s0 + row;
    float4 v = *(const float4*)(Shat + (size_t)grow * kNT + t0 + c4 * 4);
    float m = lm[row], l = ll[row];
    float4 wv;
    wv.x = __expf(v.x - m) * l;
    wv.y = __expf(v.y - m) * l;
    wv.z = __expf(v.z - m) * l;
    wv.w = __expf(v.w - m) * l;
    *(float4*)&Wt[row * 64 + c4 * 4] = wv;
  }
#pragma unroll
  for (int k2 = 0; k2 < 2; ++k2) {
    int idx = tid + k2 * 256;
    int row = idx >> 3, c4 = idx & 7;
    float4 v = *(const float4*)(ri + (size_t)(b * kNS + s0 + row) * kR + c4 * 4);
    *(float4*)&rch[row * 32 + c4 * 4] = v;
  }
  __syncthreads();
  int t_l = tid & 63, jg = tid >> 6;
  float acc[8] = {};
  for (int s = 0; s < 64; ++s) {
    float wv = Wt[s * 64 + t_l];
    float4 ra = *(const float4*)&rch[s * 32 + jg * 8];
    float4 rb = *(const float4*)&rch[s * 32 + jg * 8 + 4];
    acc[0] += wv * ra.x; acc[1] += wv * ra.y; acc[2] += wv * ra.z; acc[3] += wv * ra.w;
    acc[4] += wv * rb.x; acc[5] += wv * rb.y; acc[6] += wv * rb.z; acc[7] += wv * rb.w;
  }
  // j-major: part[cs][j][gcol] -> coalesced dword stores (lanes = consecutive cols)
  int gcol = b * kNT + t0 + t_l;
  float* dst = part + (size_t)cs * kChunkStride + (size_t)jg * 8 * kN + gcol;
#pragma unroll
  for (int q = 0; q < 8; ++q) dst[(size_t)q * kN] = acc[q];
}

// ---------------- reduce 8 partial chunks -> rt[col*32+j] ----------------
__global__ __launch_bounds__(256) void k_red(const float* __restrict__ part,
                                             float* __restrict__ rt) {
  int idx = blockIdx.x * 256 + threadIdx.x;  // 65536 = 32 j x 2048 cols
  int j = idx >> 11, col = idx & (kN - 1);
  float s = 0.f;
#pragma unroll
  for (int cs = 0; cs < 8; ++cs) s += part[(size_t)cs * kChunkStride + idx];
  rt[(size_t)col * kR + j] = s;
}

// ---------------- psi2: Ps = psi_s(r_i)@mw1+mb1 ; Pt = psi_t(rt)@mw1 -------
__device__ __forceinline__ void psi2_node(
    int n, const float* __restrict__ vin, const int* __restrict__ sr,
    const float* __restrict__ ew, const int* __restrict__ o,
    const float* __restrict__ W2, const float* __restrict__ mw1,
    const float* __restrict__ mb1, float* __restrict__ Pout) {
  int lane = threadIdx.x & 63;
  int f = lane & 31, hh = lane >> 5;
  int beg = o[n], end = o[n + 1];
  float m = 0.f;
  for (int idx = beg + hh; idx < end; idx += 2)
    m += vin[(size_t)sr[idx] * kR + f] * ew[idx];
  m += __shfl_down(m, 32, 64);
  float v = vin[(size_t)n * kR + f] + m;  // valid on lanes 0..31
  float acc = 0.f;
#pragma unroll
  for (int k = 0; k < kC2; ++k) acc += __shfl(v, k, 64) * W2[k * kC2 + f];
  float ov = fmaxf(acc, 0.f);
  float p = mb1 ? mb1[f] : 0.f;
#pragma unroll
  for (int k = 0; k < kC2; ++k) p += __shfl(ov, k, 64) * mw1[k * kC2 + f];
  if (lane < 32) Pout[(size_t)n * kC2 + f] = p;
}

__global__ __launch_bounds__(256) void k_psi2(
    const float* __restrict__ ri, const float* __restrict__ rtv,
    const int* __restrict__ srcs, const float* __restrict__ eaw,
    const int* __restrict__ off, const float* __restrict__ W2,
    const float* __restrict__ mw1, const float* __restrict__ mb1,
    float* __restrict__ Ps, float* __restrict__ Pt) {
  int n = blockIdx.x * 4 + (threadIdx.x >> 6);
  psi2_node(n, ri, srcs, eaw, off, W2, mw1, mb1, Ps);
  psi2_node(n, rtv, srcs + kE, eaw + kE, off + (kN + 1), W2, mw1, nullptr, Pt);
}

// ---- k_upd: Shat += upd over 8 s-rows x 256 t-cols; emits chunk stats ----
// grid (256 row-groups, 2 col-chunks) x 256 threads = 512 blocks (all CUs).
__global__ __launch_bounds__(256) void k_upd(
    float* __restrict__ Shat, const float* __restrict__ Ps,
    const float* __restrict__ Pt, const float* __restrict__ mw2,
    const float* __restrict__ mb2, float* __restrict__ pstatm,
    float* __restrict__ pstatl) {
  __shared__ float pts[256 * 33];  // stride 33: (tid+j)%32 banks, <=2-way
  __shared__ float red[8 * 4];
  __shared__ float lmx[8];
  int tid = threadIdx.x;
  int g0 = blockIdx.x * 8;   // global s-row base
  int cc = blockIdx.y;       // col chunk (0/1)
  int bb = g0 >> 9;          // batch
  int c0 = cc * 256;
  // stage Pt cols [c0, c0+256) of this batch into LDS, coalesced
  const float4* PtB = (const float4*)(Pt + ((size_t)bb * kNT + c0) * kC2);
#pragma unroll
  for (int k = 0; k < 8; ++k) {
    int idx = tid + k * 256;  // 2048 float4
    int col = idx >> 3, q = idx & 7;
    float4 v = PtB[idx];
    float* d = &pts[col * 33 + q * 4];
    d[0] = v.x; d[1] = v.y; d[2] = v.z; d[3] = v.w;
  }
  __syncthreads();
  float pt[32];
#pragma unroll
  for (int j = 0; j < 32; ++j) pt[j] = pts[tid * 33 + j];
  float bias = mb2[0];
  float nv[8];
#pragma unroll
  for (int s = 0; s < 8; ++s) {
    const float* psr = Ps + (size_t)(g0 + s) * kC2;  // uniform -> scalar loads
    float u = 0.f;
#pragma unroll
    for (int j = 0; j < 32; ++j) u += fmaxf(psr[j] - pt[j], 0.f) * mw2[j];
    float* p = Shat + (size_t)(g0 + s) * kNT + c0 + tid;
    float v = *p + u + bias;
    *p = v;
    nv[s] = v;
  }
  // per-row partial stats over this 256-col chunk
  int wv = tid >> 6, ln = tid & 63;
#pragma unroll
  for (int s = 0; s < 8; ++s) {
    float m = nv[s];
#pragma unroll
    for (int o2 = 32; o2; o2 >>= 1) m = fmaxf(m, __shfl_down(m, o2, 64));
    if (ln == 0) red[s * 4 + wv] = m;
  }
  __syncthreads();
  if (tid < 8) {
    lmx[tid] = fmaxf(fmaxf(red[tid * 4], red[tid * 4 + 1]),
                     fmaxf(red[tid * 4 + 2], red[tid * 4 + 3]));
  }
  __syncthreads();
#pragma unroll
  for (int s = 0; s < 8; ++s) {
    float e = __expf(nv[s] - lmx[s]);
#pragma unroll
    for (int o2 = 32; o2; o2 >>= 1) e += __shfl_down(e, o2, 64);
    if (ln == 0) red[s * 4 + wv] = e;
  }
  __syncthreads();
  if (tid < 8) {
    float l = red[tid * 4] + red[tid * 4 + 1] + red[tid * 4 + 2] + red[tid * 4 + 3];
    pstatm[cc * kN + g0 + tid] = lmx[tid];
    pstatl[cc * kN + g0 + tid] = l;
  }
}

extern "C" void kernel_launch(void* const* d_in, const int* in_sizes, int n_in,
                              void* d_out, int out_size, void* d_ws, size_t ws_size,
                              hipStream_t stream) {
  (void)in_sizes; (void)n_in; (void)out_size; (void)ws_size;
  const float* x_s = (const float*)d_in[0];
  const int* ei_s = (const int*)d_in[1];
  const float* ea_s = (const float*)d_in[2];
  const float* x_t = (const float*)d_in[4];
  const int* ei_t = (const int*)d_in[5];
  const float* ea_t = (const float*)d_in[6];
  const float* W1 = (const float*)d_in[8];
  const float* W2 = (const float*)d_in[9];
  const float* mw1 = (const float*)d_in[10];
  const float* mb1 = (const float*)d_in[11];
  const float* mw2 = (const float*)d_in[12];
  const float* mb2 = (const float*)d_in[13];
  const float* r = (const float*)d_in[14];
  float* out = (float*)d_out;

  char* w = (char*)d_ws;
  auto alloc = [&](size_t bytes) -> void* {
    void* p = (void*)w;
    w += (bytes + 255) & ~(size_t)255;
    return p;
  };
  int* deg = (int*)alloc((size_t)2 * kN * 4);
  int* off = (int*)alloc((size_t)2 * (kN + 1) * 4);
  int* cur = (int*)alloc((size_t)2 * kN * 4);
  int* srcs = (int*)alloc((size_t)2 * kE * 4);
  float* eaw = (float*)alloc((size_t)2 * kE * 4);
  float* h = (float*)alloc((size_t)2 * kN * kC1 * 4);
  float* Shat = (float*)alloc((size_t)kB * kNS * kNT * 4);
  float* pstatm = (float*)alloc((size_t)2 * kN * 4);
  float* pstatl = (float*)alloc((size_t)2 * kN * 4);
  float* rt = (float*)alloc((size_t)kN * kR * 4);
  float* Ps = (float*)alloc((size_t)kN * kC2 * 4);
  float* Pt = (float*)alloc((size_t)kN * kC2 * 4);
  float* part = (float*)alloc((size_t)8 * kChunkStride * 4);  // 2 MB

  hipMemsetAsync(deg, 0, (size_t)2 * kN * 4, stream);
  k_hist<<<dim3(kE / 256, 2), 256, 0, stream>>>(ei_s, ei_t, deg);
  k_scan<<<2, 256, 0, stream>>>(deg, off, cur);
  k_scatter<<<dim3(kE / 256, 2), 256, 0, stream>>>(ei_s, ei_t, ea_s, ea_t, cur, srcs, eaw);
  k_psi1<<<dim3(kN, 2), 128, 0, stream>>>(x_s, x_t, srcs, eaw, off, W1, h);
  k_shat0<<<dim3(8, 8, kB), 256, 0, stream>>>(h, Shat);
  k_softmax<<<kN, 256, 0, stream>>>(Shat, out, pstatm, pstatl);  // S_0 + stats
  k_rt<<<dim3(8, 8, kB), 256, 0, stream>>>(Shat, pstatm, pstatl, r, part);
  k_red<<<kChunkStride / 256, 256, 0, stream>>>(part, rt);
  for (int i = 0; i < kSteps; ++i) {
    const float* ri = r + (size_t)i * kN * kR;
    k_psi2<<<kN / 4, 256, 0, stream>>>(ri, rt, srcs, eaw, off, W2, mw1, mb1, Ps, Pt);
    k_upd<<<dim3(kN / 8, 2), 256, 0, stream>>>(Shat, Ps, Pt, mw2, mb2, pstatm, pstatl);
    if (i + 1 < kSteps) {
      k_rt<<<dim3(8, 8, kB), 256, 0, stream>>>(Shat, pstatm, pstatl,
                                               ri + (size_t)kN * kR, part);
      k_red<<<kChunkStride / 256, 256, 0, stream>>>(part, rt);
    }
  }
  k_softmax<<<kN, 256, 0, stream>>>(Shat, out + (size_t)kB * kNS * kNT, pstatm, pstatl);
}